// Round 6
// baseline (744.423 us; speedup 1.0000x reference)
//
#include <hip/hip_runtime.h>
#include <math.h>

#define N_NODES 4096
#define DIM 256
#define NH 4
#define NG 16
#define LN_EPS 1e-5f
#define TEMP 5.0f
#define RSLACK 4160     // 4096 + 64 rows of slack for tile tails
#define PS_STRIDE 72    // bf16 elems; 144 B row stride, 2-way aliasing only (free)
#define QT_MAX 24       // 24*16 = 384 max rows/graph
#define KC_MAX 6        // 6*64  = 384 max keys/graph
#define WPG (KC_MAX * QT_MAX * NH)   // 576 wave-works per graph
#define ATTN_UNITS (NG * WPG / 4)    // 2304 (4 wave-works per unit)
#define NB 1024                      // persistent blocks: 4/CU on 256 CUs

#define U0 1633   // 352 W-transpose + 1024 x-cast + 256 segmax-partial + 1 seg
#define U1 1040   // 1024 gemm (z=0,1,2,4) + 16 gcw
#define U2 (ATTN_UNITS + 256)  // attn partials + gemm z=3
#define U3 1024   // w rows (4/unit)
#define U4 4096   // combine/LN nodes

typedef __attribute__((ext_vector_type(8))) short short8;
typedef __attribute__((ext_vector_type(4))) short short4_t;
typedef __attribute__((ext_vector_type(4))) float f32x4;

__device__ __forceinline__ unsigned short f2bf(float f) {
    unsigned u = __builtin_bit_cast(unsigned, f);
    u += 0x7FFFu + ((u >> 16) & 1u);  // RNE
    return (unsigned short)(u >> 16);
}
__device__ __forceinline__ float bf2f(unsigned short u) {
    return __builtin_bit_cast(float, (unsigned)u << 16);
}
__device__ __forceinline__ float fsigmoid(float z) { return 1.f / (1.f + __expf(-z)); }
__device__ __forceinline__ float ftanh(float z) {
    float t = __expf(2.f * z);
    return (t - 1.f) / (t + 1.f);
}
__device__ __forceinline__ int seg_search(const int* __restrict__ batch, int g) {
    int lo = 0, hi = N_NODES;
    while (lo < hi) {
        int mid = (lo + hi) >> 1;
        if (batch[mid] < g) lo = mid + 1; else hi = mid;
    }
    return lo;
}

// Two-level device-scope grid barrier. cnt[0] = root, cnt[16 + 16*grp] = sub.
// Counters are zeroed by hipMemsetAsync before launch; targets are monotonic
// so one counter set serves all barriers.
__device__ __forceinline__ void gbar(unsigned* cnt, int kb) {
    __syncthreads();
    if (threadIdx.x == 0) {
        __threadfence();  // release my stores (L2 writeback, agent scope)
        unsigned* sub = cnt + 16 + (blockIdx.x >> 6) * 16;
        unsigned old = __hip_atomic_fetch_add(sub, 1u, __ATOMIC_RELEASE,
                                              __HIP_MEMORY_SCOPE_AGENT);
        if (old == (unsigned)((kb + 1) * 64 - 1))
            __hip_atomic_fetch_add(cnt, 1u, __ATOMIC_RELEASE,
                                   __HIP_MEMORY_SCOPE_AGENT);
        while (__hip_atomic_load(cnt, __ATOMIC_ACQUIRE,
                                 __HIP_MEMORY_SCOPE_AGENT) <
               (unsigned)((kb + 1) * 16))
            __builtin_amdgcn_s_sleep(1);
        __threadfence();  // invalidate stale lines before consuming
    }
    __syncthreads();
}

// ---------------- gemm unit: one 64-row x (ntn*16)-col tile ------------------
__device__ __forceinline__ void gemm_unit(
    int z, int bx, int by,
    const unsigned short* __restrict__ xb,
    const unsigned short* __restrict__ WqT, const unsigned short* __restrict__ WkT,
    const unsigned short* __restrict__ WvT, const unsigned short* __restrict__ Wv1T,
    const unsigned short* __restrict__ Wc1T,
    const float* __restrict__ bq, const float* __restrict__ bk,
    const float* __restrict__ bv, const float* __restrict__ bv1,
    const float* __restrict__ bc1, const float* __restrict__ gcw,
    const int* __restrict__ batch,
    unsigned short* __restrict__ Qb, unsigned short* __restrict__ Kb,
    unsigned short* __restrict__ Vt, unsigned short* __restrict__ Tb,
    unsigned short* __restrict__ Hvb) {
    const unsigned short* WT;
    const float* bias;
    int wstride = 256;
    switch (z) {
        case 0: WT = WqT; bias = bq; break;
        case 1: WT = WkT; bias = bk; break;
        case 2: WT = WvT; bias = bv; break;
        case 3: WT = Wc1T; bias = bc1; wstride = 512; break;
        default: WT = Wv1T; bias = bv1; break;
    }
    int ntn = (z == 4) ? 2 : 4;
    int nt0 = by * ntn;
    int tid = threadIdx.x;
    int w = tid >> 6, lane = tid & 63, m = lane & 15, quad = lane >> 4;
    int bm = bx * 64;
    int rowA = bm + 16 * w + m;
    short8 a[8];
#pragma unroll
    for (int ks = 0; ks < 8; ++ks)
        a[ks] = *(const short8*)&xb[(size_t)rowA * 256 + ks * 32 + quad * 8];
    int node0 = bm + 16 * w + quad * 4;
    int b4[4];
    if (z == 3) {
#pragma unroll
        for (int r = 0; r < 4; ++r) b4[r] = batch[node0 + r];
    }
    for (int nti = 0; nti < ntn; ++nti) {
        int nt = nt0 + nti;
        f32x4 acc = {0.f, 0.f, 0.f, 0.f};
#pragma unroll
        for (int ks = 0; ks < 8; ++ks) {
            short8 b = *(const short8*)&WT[(size_t)(nt * 16 + m) * wstride + ks * 32 + quad * 8];
            acc = __builtin_amdgcn_mfma_f32_16x16x32_bf16(a[ks], b, acc, 0, 0, 0);
        }
        int col = nt * 16 + m;
        float bb = bias[col];
        if (z == 0) {
#pragma unroll
            for (int r = 0; r < 4; ++r) Qb[(size_t)(node0 + r) * 256 + col] = f2bf(acc[r] + bb);
        } else if (z == 1) {
#pragma unroll
            for (int r = 0; r < 4; ++r) Kb[(size_t)(node0 + r) * 256 + col] = f2bf(acc[r] + bb);
        } else if (z == 2) {
            short4_t pk = {(short)f2bf(acc[0] + bb), (short)f2bf(acc[1] + bb),
                           (short)f2bf(acc[2] + bb), (short)f2bf(acc[3] + bb)};
            *(short4_t*)&Vt[(size_t)col * RSLACK + node0] = pk;
        } else if (z == 3) {
#pragma unroll
            for (int r = 0; r < 4; ++r)
                Tb[(size_t)(node0 + r) * 256 + col] =
                    f2bf(ftanh(acc[r] + bb + gcw[b4[r] * 256 + col]));
        } else {
#pragma unroll
            for (int r = 0; r < 4; ++r)
                Hvb[(size_t)(node0 + r) * 128 + col] = f2bf(fmaxf(acc[r] + bb, 0.f));
        }
    }
}

// ---------------- attention partial unit (4 wave-works) ----------------------
__device__ __forceinline__ void attn_unit(
    int u, char* smem,
    const unsigned short* __restrict__ Qb, const unsigned short* __restrict__ Kb,
    const unsigned short* __restrict__ Vt, const int* __restrict__ seg,
    unsigned short* __restrict__ Opart, float* __restrict__ Lpart) {
    unsigned short* Ps = (unsigned short*)smem;  // 4*16*PS_STRIDE bf16, wave-private slices
    int tid = threadIdx.x;
    int w = tid >> 6, lane = tid & 63, m = lane & 15, quad = lane >> 4;
    int wid = u * 4 + w;
    int g = wid / WPG;
    int r1 = wid - g * WPG;
    int kc = r1 / (QT_MAX * NH);
    int r2 = r1 - kc * (QT_MAX * NH);
    int qt = r2 >> 2, h = r2 & 3;
    int s = seg[g], e = seg[g + 1];
    int q0 = s + qt * 16;
    int k0 = s + kc * 64;
    if (q0 >= e || k0 >= e) return;

    short8 qa0 = *(const short8*)&Qb[(size_t)(q0 + m) * 256 + h * 64 + quad * 8];
    short8 qa1 = *(const short8*)&Qb[(size_t)(q0 + m) * 256 + h * 64 + 32 + quad * 8];

    f32x4 S[4];
#pragma unroll
    for (int nt = 0; nt < 4; ++nt) {
        int key = k0 + nt * 16 + m;
        short8 kb0 = *(const short8*)&Kb[(size_t)key * 256 + h * 64 + quad * 8];
        short8 kb1 = *(const short8*)&Kb[(size_t)key * 256 + h * 64 + 32 + quad * 8];
        f32x4 sa = {0.f, 0.f, 0.f, 0.f};
        sa = __builtin_amdgcn_mfma_f32_16x16x32_bf16(qa0, kb0, sa, 0, 0, 0);
        sa = __builtin_amdgcn_mfma_f32_16x16x32_bf16(qa1, kb1, sa, 0, 0, 0);
        S[nt] = sa;
    }
    int wbase = w * 16 * PS_STRIDE;
#pragma unroll
    for (int nt = 0; nt < 4; ++nt) {
        bool valid = (k0 + nt * 16 + m) < e;
#pragma unroll
        for (int r = 0; r < 4; ++r) {
            float p = valid ? __expf(S[nt][r] * 0.125f) : 0.f;
            Ps[wbase + (quad * 4 + r) * PS_STRIDE + nt * 16 + m] = f2bf(p);
        }
    }
    __builtin_amdgcn_wave_barrier();  // LDS write->read ordering, in-order DS pipe
    short8 pa0 = *(const short8*)&Ps[wbase + m * PS_STRIDE + quad * 8];
    short8 pa1 = *(const short8*)&Ps[wbase + m * PS_STRIDE + 32 + quad * 8];

    short8 ones = {16256, 16256, 16256, 16256, 16256, 16256, 16256, 16256};  // bf16 1.0
    f32x4 Lacc = {0.f, 0.f, 0.f, 0.f};
    Lacc = __builtin_amdgcn_mfma_f32_16x16x32_bf16(pa0, ones, Lacc, 0, 0, 0);
    Lacc = __builtin_amdgcn_mfma_f32_16x16x32_bf16(pa1, ones, Lacc, 0, 0, 0);
    f32x4 O[4];
#pragma unroll
    for (int nt = 0; nt < 4; ++nt) {
        const unsigned short* vrow = &Vt[(size_t)(h * 64 + nt * 16 + m) * RSLACK + k0];
        short8 vb0 = *(const short8*)&vrow[quad * 8];
        short8 vb1 = *(const short8*)&vrow[32 + quad * 8];
        f32x4 oa = {0.f, 0.f, 0.f, 0.f};
        oa = __builtin_amdgcn_mfma_f32_16x16x32_bf16(pa0, vb0, oa, 0, 0, 0);
        oa = __builtin_amdgcn_mfma_f32_16x16x32_bf16(pa1, vb1, oa, 0, 0, 0);
        O[nt] = oa;
    }
#pragma unroll
    for (int r = 0; r < 4; ++r) {
        int q = q0 + quad * 4 + r;
        if (q < e) {
            if (m == 0) Lpart[((size_t)kc * N_NODES + q) * 4 + h] = Lacc[r];
#pragma unroll
            for (int nt = 0; nt < 4; ++nt)
                Opart[((size_t)kc * N_NODES + q) * 256 + h * 64 + nt * 16 + m] =
                    f2bf(O[nt][r]);
        }
    }
}

// ================= the persistent mega kernel ================================
__global__ __launch_bounds__(256, 4) void mega_kernel(
    const float* __restrict__ x,
    const float* __restrict__ Wq, const float* __restrict__ bq,
    const float* __restrict__ Wk, const float* __restrict__ bk,
    const float* __restrict__ Wv, const float* __restrict__ bv,
    const float* __restrict__ Wv1, const float* __restrict__ bv1,
    const float* __restrict__ Wv2, const float* __restrict__ bv2,
    const float* __restrict__ Wc1, const float* __restrict__ bc1,
    const float* __restrict__ Wc2, const float* __restrict__ bc2,
    const float* __restrict__ gamma, const float* __restrict__ beta,
    const int* __restrict__ batch,
    float* __restrict__ out, float* __restrict__ att_out,
    unsigned* __restrict__ cnt, float* __restrict__ smax,
    float* __restrict__ Lpart, float* __restrict__ gcw,
    float* __restrict__ wbuf, int* __restrict__ seg,
    unsigned short* __restrict__ xb, unsigned short* __restrict__ Qb,
    unsigned short* __restrict__ Kb, unsigned short* __restrict__ Vt,
    unsigned short* __restrict__ WqT, unsigned short* __restrict__ WkT,
    unsigned short* __restrict__ WvT, unsigned short* __restrict__ Wv1T,
    unsigned short* __restrict__ Wc1T, unsigned short* __restrict__ Hvb,
    unsigned short* __restrict__ Tb, unsigned short* __restrict__ Opart) {
    __shared__ __align__(16) char smem[9472];
    int tid = threadIdx.x;
    int w = tid >> 6, lane = tid & 63;

    // ---------------- S0: W transpose, x cast, segmax partials, seg ----------
    for (int u = blockIdx.x; u < U0; u += NB) {
        if (u < 352) {
            const float* src; unsigned short* dst; int K, Nn, tX, rel;
            if (u < 64)       { src = Wq;  dst = WqT;  K = 256; Nn = 256; rel = u;      tX = 8;  }
            else if (u < 128) { src = Wk;  dst = WkT;  K = 256; Nn = 256; rel = u-64;   tX = 8;  }
            else if (u < 192) { src = Wv;  dst = WvT;  K = 256; Nn = 256; rel = u-128;  tX = 8;  }
            else if (u < 224) { src = Wv1; dst = Wv1T; K = 256; Nn = 128; rel = u-192;  tX = 8;  }
            else              { src = Wc1; dst = Wc1T; K = 512; Nn = 256; rel = u-224;  tX = 16; }
            int k0 = (rel % tX) * 32, n0 = (rel / tX) * 32;
            float (*t)[33] = (float(*)[33])smem;
            int c = tid & 31, r0 = tid >> 5;
#pragma unroll
            for (int p = 0; p < 4; ++p) {
                int rr = p * 8 + r0;
                t[rr][c] = src[(size_t)(k0 + rr) * Nn + n0 + c];
            }
            __syncthreads();
#pragma unroll
            for (int p = 0; p < 4; ++p) {
                int rr = p * 8 + r0;
                dst[(size_t)(n0 + rr) * K + k0 + c] = f2bf(t[c][rr]);
            }
            __syncthreads();
        } else if (u < 1376) {
            int base = (u - 352) * 1024 + tid * 4;
            float4 v = *(const float4*)&x[base];
            short4_t o = {(short)f2bf(v.x), (short)f2bf(v.y), (short)f2bf(v.z),
                          (short)f2bf(v.w)};
            *(short4_t*)&xb[base] = o;
        } else if (u < 1632) {
            int gg = (u - 1376) >> 4, c = (u - 1376) & 15;
            int s = seg_search(batch, gg), e = seg_search(batch, gg + 1);
            float mx = -INFINITY;
            for (int i = s + c; i < e; i += 16) mx = fmaxf(mx, x[(size_t)i * DIM + tid]);
            smax[(size_t)(u - 1376) * 256 + tid] = mx;
        } else {
            if (tid <= NG) seg[tid] = seg_search(batch, tid);
        }
    }
    gbar(cnt, 0);

    // ---------------- S1: projections Q,K,V,Hv + gcw -------------------------
    for (int u = blockIdx.x; u < U1; u += NB) {
        if (u < 1024) {
            int zi = u >> 8;
            int z = (zi == 3) ? 4 : zi;
            int r = u & 255;
            gemm_unit(z, r & 63, r >> 6, xb, WqT, WkT, WvT, Wv1T, Wc1T,
                      bq, bk, bv, bv1, bc1, gcw, batch, Qb, Kb, Vt, Tb, Hvb);
        } else {
            int g = u - 1024;
            float* gl = (float*)smem;
            float mx = smax[(size_t)(g * 16) * 256 + tid];
#pragma unroll
            for (int c = 1; c < 16; ++c)
                mx = fmaxf(mx, smax[(size_t)(g * 16 + c) * 256 + tid]);
            gl[tid] = bf2f(f2bf(mx));  // bf16-rounded, consistent with x cast
            __syncthreads();
            float a0 = 0.f, a1 = 0.f, a2 = 0.f, a3 = 0.f;
            for (int k = 0; k < 256; k += 4) {
                a0 += gl[k + 0] * Wc1[(size_t)(256 + k + 0) * 256 + tid];
                a1 += gl[k + 1] * Wc1[(size_t)(256 + k + 1) * 256 + tid];
                a2 += gl[k + 2] * Wc1[(size_t)(256 + k + 2) * 256 + tid];
                a3 += gl[k + 3] * Wc1[(size_t)(256 + k + 3) * 256 + tid];
            }
            gcw[g * 256 + tid] = (a0 + a1) + (a2 + a3);
            __syncthreads();
        }
    }
    gbar(cnt, 1);

    // ---------------- S2: attention partials + Tb projection -----------------
    for (int u = blockIdx.x; u < U2; u += NB) {
        if (u < ATTN_UNITS) {
            attn_unit(u, smem, Qb, Kb, Vt, seg, Opart, Lpart);
        } else {
            int r = u - ATTN_UNITS;
            gemm_unit(3, r & 63, r >> 6, xb, WqT, WkT, WvT, Wv1T, Wc1T,
                      bq, bk, bv, bv1, bc1, gcw, batch, Qb, Kb, Vt, Tb, Hvb);
        }
    }
    gbar(cnt, 2);

    // ---------------- S3: w --------------------------------------------------
    for (int u = blockIdx.x; u < U3; u += NB) {
        int row = u * 4 + w;
        ushort2 hv = *(const ushort2*)&Hvb[(size_t)row * 128 + lane * 2];
        float v = bf2f(hv.x) * Wv2[lane * 2] + bf2f(hv.y) * Wv2[lane * 2 + 1];
        short4_t tv = *(const short4_t*)&Tb[(size_t)row * 256 + lane * 4];
        float c = 0.f;
#pragma unroll
        for (int j = 0; j < 4; ++j)
            c += bf2f((unsigned short)tv[j]) * Wc2[lane * 4 + j];
#pragma unroll
        for (int mm = 32; mm; mm >>= 1) {
            v += __shfl_xor(v, mm);
            c += __shfl_xor(c, mm);
        }
        if (lane == 0)
            wbuf[row] = 0.6f * fsigmoid(v + bv2[0]) + 0.3f * fsigmoid(c + bc2[0]) +
                        0.1f / 4096.f;
    }
    gbar(cnt, 3);

    // ---------------- S4: att softmax + combine + residual + LN --------------
    for (int u = blockIdx.x; u < U4; u += NB) {
        int n = u;
        int g = batch[n];
        int s = seg[g], e = seg[g + 1];
        float* r1 = (float*)smem;
        float* r2 = r1 + 4;
        float w1 = (s + tid < e) ? wbuf[s + tid] * TEMP : -1e30f;
        float w2 = (s + 256 + tid < e) ? wbuf[s + 256 + tid] * TEMP : -1e30f;
        float mx = fmaxf(w1, w2);
#pragma unroll
        for (int k2 = 32; k2; k2 >>= 1) mx = fmaxf(mx, __shfl_xor(mx, k2));
        if ((tid & 63) == 0) r1[tid >> 6] = mx;
        __syncthreads();
        float m = fmaxf(fmaxf(r1[0], r1[1]), fmaxf(r1[2], r1[3]));
        float sm = ((s + tid < e) ? __expf(w1 - m) : 0.f) +
                   ((s + 256 + tid < e) ? __expf(w2 - m) : 0.f);
#pragma unroll
        for (int k2 = 32; k2; k2 >>= 1) sm += __shfl_xor(sm, k2);
        __syncthreads();
        if ((tid & 63) == 0) r2[tid >> 6] = sm;
        __syncthreads();
        float ssum = r2[0] + r2[1] + r2[2] + r2[3];
        float att_n = __expf(wbuf[n] * TEMP - m) / ssum;
        if (tid == 0) att_out[n] = att_n;
        int h = tid >> 6;
        float L = 0.f, O = 0.f;
        for (int c = 0; c < KC_MAX; ++c) {
            if (s + c * 64 >= e) break;
            L += Lpart[((size_t)c * N_NODES + n) * 4 + h];
            O += bf2f(Opart[((size_t)c * N_NODES + n) * 256 + tid]);
        }
        float o = (O / L) * att_n + x[(size_t)n * 256 + tid];
        float s1 = o, s2 = o * o;
#pragma unroll
        for (int k2 = 32; k2; k2 >>= 1) {
            s1 += __shfl_xor(s1, k2);
            s2 += __shfl_xor(s2, k2);
        }
        __syncthreads();
        if ((tid & 63) == 0) { r1[tid >> 6] = s1; r2[tid >> 6] = s2; }
        __syncthreads();
        float mu = (r1[0] + r1[1] + r1[2] + r1[3]) * (1.f / 256.f);
        float ms = (r2[0] + r2[1] + r2[2] + r2[3]) * (1.f / 256.f);
        float rs = rsqrtf(ms - mu * mu + LN_EPS);
        out[(size_t)n * 256 + tid] = (o - mu) * rs * gamma[tid] + beta[tid];
        __syncthreads();  // guard r1/r2 reuse by next unit
    }
}

extern "C" void kernel_launch(void* const* d_in, const int* in_sizes, int n_in,
                              void* d_out, int out_size, void* d_ws, size_t ws_size,
                              hipStream_t stream) {
    const float* x     = (const float*)d_in[0];
    const float* Wq    = (const float*)d_in[1];
    const float* bq    = (const float*)d_in[2];
    const float* Wk    = (const float*)d_in[3];
    const float* bk    = (const float*)d_in[4];
    const float* Wv    = (const float*)d_in[5];
    const float* bv    = (const float*)d_in[6];
    const float* Wv1   = (const float*)d_in[7];
    const float* bv1   = (const float*)d_in[8];
    const float* Wv2   = (const float*)d_in[9];
    const float* bv2   = (const float*)d_in[10];
    const float* Wc1   = (const float*)d_in[11];
    const float* bc1   = (const float*)d_in[12];
    const float* Wc2   = (const float*)d_in[13];
    const float* bc2   = (const float*)d_in[14];
    const float* gamma = (const float*)d_in[15];
    const float* beta  = (const float*)d_in[16];
    const int*   batch = (const int*)d_in[17];

    float* out = (float*)d_out;        // [N, D]
    float* att = out + N_NODES * DIM;  // [N]

    unsigned* cnt = (unsigned*)d_ws;   // 4096 B of barrier counters
    float* f32r  = (float*)((char*)d_ws + 4096);
    float* smax  = f32r;                           // 256*256
    float* Lpart = smax + 256 * 256;               // 6*4096*4
    float* gcw   = Lpart + KC_MAX * N_NODES * 4;   // 16*256
    float* wbuf  = gcw + NG * DIM;                 // 4096
    int*   seg   = (int*)(wbuf + N_NODES);         // 32 ints
    unsigned short* bws   = (unsigned short*)(seg + 32);
    unsigned short* xb    = bws;                   // 4096*256
    unsigned short* Qb    = xb + N_NODES * DIM;    // 4160*256
    unsigned short* Kb    = Qb + RSLACK * DIM;     // 4160*256
    unsigned short* Vt    = Kb + RSLACK * DIM;     // 256*4160
    unsigned short* WqT   = Vt + DIM * RSLACK;     // 256*256
    unsigned short* WkT   = WqT + DIM * DIM;
    unsigned short* WvT   = WkT + DIM * DIM;
    unsigned short* Wv1T  = WvT + DIM * DIM;       // 128*256
    unsigned short* Wc1T  = Wv1T + 128 * DIM;      // 256*512
    unsigned short* Hvb   = Wc1T + DIM * 512;      // 4096*128
    unsigned short* Tb    = Hvb + N_NODES * 128;   // 4096*256
    unsigned short* Opart = Tb + N_NODES * DIM;    // 6*4096*256

    hipMemsetAsync(d_ws, 0, 4096, stream);  // zero barrier counters (capturable)
    mega_kernel<<<NB, 256, 0, stream>>>(
        x, Wq, bq, Wk, bk, Wv, bv, Wv1, bv1, Wv2, bv2, Wc1, bc1, Wc2, bc2,
        gamma, beta, batch, out, att, cnt, smax, Lpart, gcw, wbuf, seg,
        xb, Qb, Kb, Vt, WqT, WkT, WvT, Wv1T, Wc1T, Hvb, Tb, Opart);
}

// Round 7
// 167.674 us; speedup vs baseline: 4.4397x; 4.4397x over previous
//
#include <hip/hip_runtime.h>
#include <math.h>

#define N_NODES 4096
#define DIM 256
#define NH 4
#define NG 16
#define LN_EPS 1e-5f
#define TEMP 5.0f
#define RSLACK 4160     // 4096 + 64 rows of slack for tile tails
#define PS_STRIDE 72    // bf16 elems; 144 B row stride, 2-way aliasing only (free)
#define QT_MAX 24       // 24*16 = 384 max rows/graph
#define KC_MAX 6        // 6*64  = 384 max keys/graph
#define WPG (KC_MAX * QT_MAX * NH)   // 576 wave-works per graph
#define ATTN_UNITS (NG * WPG / 4)    // 2304 (4 wave-works per block)

typedef __attribute__((ext_vector_type(8))) short short8;
typedef __attribute__((ext_vector_type(4))) short short4_t;
typedef __attribute__((ext_vector_type(4))) float f32x4;

__device__ __forceinline__ unsigned short f2bf(float f) {
    unsigned u = __builtin_bit_cast(unsigned, f);
    u += 0x7FFFu + ((u >> 16) & 1u);  // RNE
    return (unsigned short)(u >> 16);
}
__device__ __forceinline__ float bf2f(unsigned short u) {
    return __builtin_bit_cast(float, (unsigned)u << 16);
}
__device__ __forceinline__ float fsigmoid(float z) { return 1.f / (1.f + __expf(-z)); }
__device__ __forceinline__ float ftanh(float z) {
    float t = __expf(2.f * z);
    return (t - 1.f) / (t + 1.f);
}
__device__ __forceinline__ int seg_search(const int* __restrict__ batch, int g) {
    int lo = 0, hi = N_NODES;
    while (lo < hi) {
        int mid = (lo + hi) >> 1;
        if (batch[mid] < g) lo = mid + 1; else hi = mid;
    }
    return lo;
}

// ================= K1: W transpose + x cast + segmax partials + seg ==========
// blocks [0,352) transpose; [352,1376) x cast; [1376,1632) segmax partial;
// 1632: seg array
__global__ __launch_bounds__(256) void prep_kernel(
    const float* __restrict__ x, const float* __restrict__ Wq,
    const float* __restrict__ Wk, const float* __restrict__ Wv,
    const float* __restrict__ Wv1, const float* __restrict__ Wc1,
    const int* __restrict__ batch,
    unsigned short* __restrict__ xb, unsigned short* __restrict__ WqT,
    unsigned short* __restrict__ WkT, unsigned short* __restrict__ WvT,
    unsigned short* __restrict__ Wv1T, unsigned short* __restrict__ Wc1T,
    float* __restrict__ smax, int* __restrict__ seg) {
    int id = blockIdx.x, tid = threadIdx.x;
    if (id == 1632) {
        if (tid <= NG) seg[tid] = seg_search(batch, tid);
        return;
    }
    if (id >= 1376) {  // segmax partial: graph gg, row-slice c of 16
        int u = id - 1376;
        int gg = u >> 4, c = u & 15;
        int s = seg_search(batch, gg), e = seg_search(batch, gg + 1);
        float mx = -INFINITY;
        for (int i = s + c; i < e; i += 16) mx = fmaxf(mx, x[(size_t)i * DIM + tid]);
        smax[(size_t)u * 256 + tid] = mx;
        return;
    }
    if (id >= 352) {  // x cast
        int base = (id - 352) * 1024 + tid * 4;
        float4 v = *(const float4*)&x[base];
        short4_t o = {(short)f2bf(v.x), (short)f2bf(v.y), (short)f2bf(v.z), (short)f2bf(v.w)};
        *(short4_t*)&xb[base] = o;
        return;
    }
    const float* src; unsigned short* dst; int K, Nn, tX, rel;
    if (id < 64)       { src = Wq;  dst = WqT;  K = 256; Nn = 256; rel = id;      tX = 8;  }
    else if (id < 128) { src = Wk;  dst = WkT;  K = 256; Nn = 256; rel = id-64;   tX = 8;  }
    else if (id < 192) { src = Wv;  dst = WvT;  K = 256; Nn = 256; rel = id-128;  tX = 8;  }
    else if (id < 224) { src = Wv1; dst = Wv1T; K = 256; Nn = 128; rel = id-192;  tX = 8;  }
    else               { src = Wc1; dst = Wc1T; K = 512; Nn = 256; rel = id-224;  tX = 16; }
    int k0 = (rel % tX) * 32, n0 = (rel / tX) * 32;
    __shared__ float t[32][33];
    int c = tid & 31, r0 = tid >> 5;
#pragma unroll
    for (int p = 0; p < 4; ++p) {
        int rr = p * 8 + r0;
        t[rr][c] = src[(size_t)(k0 + rr) * Nn + n0 + c];
    }
    __syncthreads();
#pragma unroll
    for (int p = 0; p < 4; ++p) {
        int rr = p * 8 + r0;
        dst[(size_t)(n0 + rr) * K + k0 + c] = f2bf(t[c][rr]);
    }
}

// ---------------- shared gemm unit -------------------------------------------
// z=0 Qb, 1 Kb, 2 Vt (transposed), 3 cacc += tanh(x@Wc1_top+bc1+gcw[b])·Wc2,
// 4 vacc += relu(x@Wv1+bv1)·Wv2
__device__ __forceinline__ void gemm_unit(
    int z, int bx, int by,
    const unsigned short* __restrict__ xb,
    const unsigned short* __restrict__ WqT, const unsigned short* __restrict__ WkT,
    const unsigned short* __restrict__ WvT, const unsigned short* __restrict__ Wv1T,
    const unsigned short* __restrict__ Wc1T,
    const float* __restrict__ bq, const float* __restrict__ bk,
    const float* __restrict__ bv, const float* __restrict__ bv1,
    const float* __restrict__ bc1, const float* __restrict__ gcw,
    const float* __restrict__ Wv2, const float* __restrict__ Wc2,
    const int* __restrict__ batch,
    unsigned short* __restrict__ Qb, unsigned short* __restrict__ Kb,
    unsigned short* __restrict__ Vt, float* __restrict__ vacc,
    float* __restrict__ cacc) {
    const unsigned short* WT;
    const float* bias;
    int wstride = 256;
    switch (z) {
        case 0: WT = WqT; bias = bq; break;
        case 1: WT = WkT; bias = bk; break;
        case 2: WT = WvT; bias = bv; break;
        case 3: WT = Wc1T; bias = bc1; wstride = 512; break;
        default: WT = Wv1T; bias = bv1; break;
    }
    int ntn = (z == 4) ? 2 : 4;
    int nt0 = by * ntn;
    int tid = threadIdx.x;
    int w = tid >> 6, lane = tid & 63, m = lane & 15, quad = lane >> 4;
    int bm = bx * 64;
    int rowA = bm + 16 * w + m;
    short8 a[8];
#pragma unroll
    for (int ks = 0; ks < 8; ++ks)
        a[ks] = *(const short8*)&xb[(size_t)rowA * 256 + ks * 32 + quad * 8];
    int node0 = bm + 16 * w + quad * 4;
    int b4[4];
    if (z == 3) {
#pragma unroll
        for (int r = 0; r < 4; ++r) b4[r] = batch[node0 + r];
    }
    for (int nti = 0; nti < ntn; ++nti) {
        int nt = nt0 + nti;
        f32x4 acc = {0.f, 0.f, 0.f, 0.f};
#pragma unroll
        for (int ks = 0; ks < 8; ++ks) {
            short8 b = *(const short8*)&WT[(size_t)(nt * 16 + m) * wstride + ks * 32 + quad * 8];
            acc = __builtin_amdgcn_mfma_f32_16x16x32_bf16(a[ks], b, acc, 0, 0, 0);
        }
        int col = nt * 16 + m;
        float bb = bias[col];
        if (z == 0) {
#pragma unroll
            for (int r = 0; r < 4; ++r) Qb[(size_t)(node0 + r) * 256 + col] = f2bf(acc[r] + bb);
        } else if (z == 1) {
#pragma unroll
            for (int r = 0; r < 4; ++r) Kb[(size_t)(node0 + r) * 256 + col] = f2bf(acc[r] + bb);
        } else if (z == 2) {
            short4_t pk = {(short)f2bf(acc[0] + bb), (short)f2bf(acc[1] + bb),
                           (short)f2bf(acc[2] + bb), (short)f2bf(acc[3] + bb)};
            *(short4_t*)&Vt[(size_t)col * RSLACK + node0] = pk;
        } else if (z == 3) {
            float wc = Wc2[col];
#pragma unroll
            for (int r = 0; r < 4; ++r) {
                float p = ftanh(acc[r] + bb + gcw[b4[r] * 256 + col]) * wc;
#pragma unroll
                for (int mm = 1; mm < 16; mm <<= 1) p += __shfl_xor(p, mm);
                if (m == 0) atomicAdd(&cacc[node0 + r], p);
            }
        } else {
            float wv = Wv2[col];
#pragma unroll
            for (int r = 0; r < 4; ++r) {
                float p = fmaxf(acc[r] + bb, 0.f) * wv;
#pragma unroll
                for (int mm = 1; mm < 16; mm <<= 1) p += __shfl_xor(p, mm);
                if (m == 0) atomicAdd(&vacc[node0 + r], p);
            }
        }
    }
}

// ================= K2: gcw reduce (16) + Q/K/V/Hv GEMMs (1024) ===============
__global__ __launch_bounds__(256) void gemm_kernel(
    const unsigned short* __restrict__ xb, const float* __restrict__ smax,
    const float* __restrict__ Wc1,
    const unsigned short* __restrict__ WqT, const unsigned short* __restrict__ WkT,
    const unsigned short* __restrict__ WvT, const unsigned short* __restrict__ Wv1T,
    const unsigned short* __restrict__ Wc1T,
    const float* __restrict__ bq, const float* __restrict__ bk,
    const float* __restrict__ bv, const float* __restrict__ bv1,
    const float* __restrict__ bc1, const float* __restrict__ Wv2,
    const float* __restrict__ Wc2, const int* __restrict__ batch,
    unsigned short* __restrict__ Qb, unsigned short* __restrict__ Kb,
    unsigned short* __restrict__ Vt, float* __restrict__ vacc,
    float* __restrict__ gcw) {
    int tid = threadIdx.x;
    if (blockIdx.x < 16) {  // gcw[g][tid] = sum_k max_c(smax) * Wc1[256+k][tid]
        int g = blockIdx.x;
        __shared__ float gl[256];
        float mx = smax[(size_t)(g * 16) * 256 + tid];
#pragma unroll
        for (int c = 1; c < 16; ++c)
            mx = fmaxf(mx, smax[(size_t)(g * 16 + c) * 256 + tid]);
        gl[tid] = bf2f(f2bf(mx));  // bf16-rounded, consistent with x cast
        __syncthreads();
        float a0 = 0.f, a1 = 0.f, a2 = 0.f, a3 = 0.f;
        for (int k = 0; k < 256; k += 4) {
            a0 += gl[k + 0] * Wc1[(size_t)(256 + k + 0) * 256 + tid];
            a1 += gl[k + 1] * Wc1[(size_t)(256 + k + 1) * 256 + tid];
            a2 += gl[k + 2] * Wc1[(size_t)(256 + k + 2) * 256 + tid];
            a3 += gl[k + 3] * Wc1[(size_t)(256 + k + 3) * 256 + tid];
        }
        gcw[g * 256 + tid] = (a0 + a1) + (a2 + a3);
        return;
    }
    int u = blockIdx.x - 16;
    int zi = u >> 8;
    int z = (zi == 3) ? 4 : zi;
    int r = u & 255;
    gemm_unit(z, r & 63, r >> 6, xb, WqT, WkT, WvT, Wv1T, Wc1T,
              bq, bk, bv, bv1, bc1, nullptr, Wv2, Wc2, batch,
              Qb, Kb, Vt, vacc, nullptr);
}

// ================= K3: Tb/cacc GEMM (256) + attention partials (2304) ========
__global__ __launch_bounds__(256) void attn_kernel(
    const unsigned short* __restrict__ xb,
    const unsigned short* __restrict__ Qb, const unsigned short* __restrict__ Kb,
    const unsigned short* __restrict__ Vt, const int* __restrict__ seg,
    const unsigned short* __restrict__ Wc1T, const float* __restrict__ bc1,
    const float* __restrict__ gcw, const float* __restrict__ Wc2,
    const int* __restrict__ batch,
    unsigned short* __restrict__ Opart, float* __restrict__ Lpart,
    float* __restrict__ cacc) {
    int tid = threadIdx.x;
    if (blockIdx.x < 256) {
        int r = blockIdx.x;
        gemm_unit(3, r & 63, r >> 6, xb, nullptr, nullptr, nullptr, nullptr, Wc1T,
                  nullptr, nullptr, nullptr, nullptr, bc1, gcw, nullptr, Wc2, batch,
                  nullptr, nullptr, nullptr, nullptr, cacc);
        return;
    }
    // ---- attention partial: wave-work (g, kc, qt, h) ----
    __shared__ unsigned short Ps[4 * 16 * PS_STRIDE];
    int w = tid >> 6, lane = tid & 63, m = lane & 15, quad = lane >> 4;
    int wid = (blockIdx.x - 256) * 4 + w;
    int g = wid / WPG;
    int r1 = wid - g * WPG;
    int kc = r1 / (QT_MAX * NH);
    int r2 = r1 - kc * (QT_MAX * NH);
    int qt = r2 >> 2, h = r2 & 3;
    int s = seg[g], e = seg[g + 1];
    int q0 = s + qt * 16;
    int k0 = s + kc * 64;
    if (q0 >= e || k0 >= e) return;

    short8 qa0 = *(const short8*)&Qb[(size_t)(q0 + m) * 256 + h * 64 + quad * 8];
    short8 qa1 = *(const short8*)&Qb[(size_t)(q0 + m) * 256 + h * 64 + 32 + quad * 8];

    f32x4 S[4];
#pragma unroll
    for (int nt = 0; nt < 4; ++nt) {
        int key = k0 + nt * 16 + m;
        short8 kb0 = *(const short8*)&Kb[(size_t)key * 256 + h * 64 + quad * 8];
        short8 kb1 = *(const short8*)&Kb[(size_t)key * 256 + h * 64 + 32 + quad * 8];
        f32x4 sa = {0.f, 0.f, 0.f, 0.f};
        sa = __builtin_amdgcn_mfma_f32_16x16x32_bf16(qa0, kb0, sa, 0, 0, 0);
        sa = __builtin_amdgcn_mfma_f32_16x16x32_bf16(qa1, kb1, sa, 0, 0, 0);
        S[nt] = sa;
    }
    int wbase = w * 16 * PS_STRIDE;
#pragma unroll
    for (int nt = 0; nt < 4; ++nt) {
        bool valid = (k0 + nt * 16 + m) < e;
#pragma unroll
        for (int r = 0; r < 4; ++r) {
            float p = valid ? __expf(S[nt][r] * 0.125f) : 0.f;
            Ps[wbase + (quad * 4 + r) * PS_STRIDE + nt * 16 + m] = f2bf(p);
        }
    }
    __builtin_amdgcn_wave_barrier();  // LDS write->read ordering, in-order DS pipe
    short8 pa0 = *(const short8*)&Ps[wbase + m * PS_STRIDE + quad * 8];
    short8 pa1 = *(const short8*)&Ps[wbase + m * PS_STRIDE + 32 + quad * 8];

    short8 ones = {16256, 16256, 16256, 16256, 16256, 16256, 16256, 16256};  // bf16 1.0
    f32x4 Lacc = {0.f, 0.f, 0.f, 0.f};
    Lacc = __builtin_amdgcn_mfma_f32_16x16x32_bf16(pa0, ones, Lacc, 0, 0, 0);
    Lacc = __builtin_amdgcn_mfma_f32_16x16x32_bf16(pa1, ones, Lacc, 0, 0, 0);
    f32x4 O[4];
#pragma unroll
    for (int nt = 0; nt < 4; ++nt) {
        const unsigned short* vrow = &Vt[(size_t)(h * 64 + nt * 16 + m) * RSLACK + k0];
        short8 vb0 = *(const short8*)&vrow[quad * 8];
        short8 vb1 = *(const short8*)&vrow[32 + quad * 8];
        f32x4 oa = {0.f, 0.f, 0.f, 0.f};
        oa = __builtin_amdgcn_mfma_f32_16x16x32_bf16(pa0, vb0, oa, 0, 0, 0);
        oa = __builtin_amdgcn_mfma_f32_16x16x32_bf16(pa1, vb1, oa, 0, 0, 0);
        O[nt] = oa;
    }
#pragma unroll
    for (int r = 0; r < 4; ++r) {
        int q = q0 + quad * 4 + r;
        if (q < e) {
            if (m == 0) Lpart[((size_t)kc * N_NODES + q) * 4 + h] = Lacc[r];
#pragma unroll
            for (int nt = 0; nt < 4; ++nt)
                Opart[((size_t)kc * N_NODES + q) * 256 + h * 64 + nt * 16 + m] =
                    f2bf(O[nt][r]);
        }
    }
}

// ================= K4: w + graph softmax + combine + residual + LN ===========
__global__ __launch_bounds__(256) void final_kernel(
    const unsigned short* __restrict__ Opart, const float* __restrict__ Lpart,
    const float* __restrict__ x, const float* __restrict__ vacc,
    const float* __restrict__ cacc, const float* __restrict__ bv2,
    const float* __restrict__ bc2, const float* __restrict__ gamma,
    const float* __restrict__ beta, const int* __restrict__ batch,
    const int* __restrict__ seg, float* __restrict__ out,
    float* __restrict__ att_out) {
    int n = blockIdx.x;
    int tid = threadIdx.x;
    int g = batch[n];
    int s = seg[g], e = seg[g + 1];
    float vb = bv2[0], cb = bc2[0];
    __shared__ float r1[4], r2[4];
    // w*TEMP for this graph, recomputed from vacc/cacc (2 sigmoids/node)
    int i1 = s + tid, i2 = s + 256 + tid;
    float w1 = (i1 < e) ? TEMP * (0.6f * fsigmoid(vacc[i1] + vb) +
                                  0.3f * fsigmoid(cacc[i1] + cb) + 0.1f / 4096.f)
                        : -1e30f;
    float w2 = (i2 < e) ? TEMP * (0.6f * fsigmoid(vacc[i2] + vb) +
                                  0.3f * fsigmoid(cacc[i2] + cb) + 0.1f / 4096.f)
                        : -1e30f;
    float mx = fmaxf(w1, w2);
#pragma unroll
    for (int k2 = 32; k2; k2 >>= 1) mx = fmaxf(mx, __shfl_xor(mx, k2));
    if ((tid & 63) == 0) r1[tid >> 6] = mx;
    __syncthreads();
    float m = fmaxf(fmaxf(r1[0], r1[1]), fmaxf(r1[2], r1[3]));
    float sm = ((i1 < e) ? __expf(w1 - m) : 0.f) + ((i2 < e) ? __expf(w2 - m) : 0.f);
#pragma unroll
    for (int k2 = 32; k2; k2 >>= 1) sm += __shfl_xor(sm, k2);
    __syncthreads();
    if ((tid & 63) == 0) r2[tid >> 6] = sm;
    __syncthreads();
    float ssum = r2[0] + r2[1] + r2[2] + r2[3];
    float w5n = TEMP * (0.6f * fsigmoid(vacc[n] + vb) + 0.3f * fsigmoid(cacc[n] + cb) +
                        0.1f / 4096.f);
    float att_n = __expf(w5n - m) / ssum;
    if (tid == 0) att_out[n] = att_n;
    // combine key-chunk partials (unconditional masked loads - no serial break)
    int h = tid >> 6;
    float L = 0.f, O = 0.f;
#pragma unroll
    for (int c = 0; c < KC_MAX; ++c) {
        bool valid = (s + c * 64) < e;
        float lv = Lpart[((size_t)c * N_NODES + n) * 4 + h];
        float ov = bf2f(Opart[((size_t)c * N_NODES + n) * 256 + tid]);
        if (valid) { L += lv; O += ov; }
    }
    float o = (O / L) * att_n + x[(size_t)n * 256 + tid];
    float s1 = o, s2 = o * o;
#pragma unroll
    for (int k2 = 32; k2; k2 >>= 1) {
        s1 += __shfl_xor(s1, k2);
        s2 += __shfl_xor(s2, k2);
    }
    __syncthreads();
    if ((tid & 63) == 0) { r1[tid >> 6] = s1; r2[tid >> 6] = s2; }
    __syncthreads();
    float mu = (r1[0] + r1[1] + r1[2] + r1[3]) * (1.f / 256.f);
    float ms = (r2[0] + r2[1] + r2[2] + r2[3]) * (1.f / 256.f);
    float rs = rsqrtf(ms - mu * mu + LN_EPS);
    out[(size_t)n * 256 + tid] = (o - mu) * rs * gamma[tid] + beta[tid];
}

extern "C" void kernel_launch(void* const* d_in, const int* in_sizes, int n_in,
                              void* d_out, int out_size, void* d_ws, size_t ws_size,
                              hipStream_t stream) {
    const float* x     = (const float*)d_in[0];
    const float* Wq    = (const float*)d_in[1];
    const float* bq    = (const float*)d_in[2];
    const float* Wk    = (const float*)d_in[3];
    const float* bk    = (const float*)d_in[4];
    const float* Wv    = (const float*)d_in[5];
    const float* bv    = (const float*)d_in[6];
    const float* Wv1   = (const float*)d_in[7];
    const float* bv1   = (const float*)d_in[8];
    const float* Wv2   = (const float*)d_in[9];
    const float* bv2   = (const float*)d_in[10];
    const float* Wc1   = (const float*)d_in[11];
    const float* bc1   = (const float*)d_in[12];
    const float* Wc2   = (const float*)d_in[13];
    const float* bc2   = (const float*)d_in[14];
    const float* gamma = (const float*)d_in[15];
    const float* beta  = (const float*)d_in[16];
    const int*   batch = (const int*)d_in[17];

    float* out = (float*)d_out;        // [N, D]
    float* att = out + N_NODES * DIM;  // [N]

    // zeroed region first (one small memset covers vacc+cacc)
    float* vacc  = (float*)d_ws;                   // 4096
    float* cacc  = vacc + N_NODES;                 // 4096
    float* smax  = cacc + N_NODES;                 // 256*256
    float* Lpart = smax + 256 * 256;               // 6*4096*4
    float* gcw   = Lpart + KC_MAX * N_NODES * 4;   // 16*256
    int*   seg   = (int*)(gcw + NG * DIM);         // 32 ints
    unsigned short* bws   = (unsigned short*)(seg + 32);
    unsigned short* xb    = bws;                   // 4096*256
    unsigned short* Qb    = xb + N_NODES * DIM;    // 4160*256
    unsigned short* Kb    = Qb + RSLACK * DIM;     // 4160*256
    unsigned short* Vt    = Kb + RSLACK * DIM;     // 256*4160
    unsigned short* WqT   = Vt + DIM * RSLACK;     // 256*256
    unsigned short* WkT   = WqT + DIM * DIM;
    unsigned short* WvT   = WkT + DIM * DIM;
    unsigned short* Wv1T  = WvT + DIM * DIM;       // 128*256
    unsigned short* Wc1T  = Wv1T + 128 * DIM;      // 256*512
    unsigned short* Opart = Wc1T + DIM * 512;      // 6*4096*256

    hipMemsetAsync(d_ws, 0, 2 * N_NODES * sizeof(float), stream);  // vacc, cacc
    prep_kernel<<<1633, 256, 0, stream>>>(x, Wq, Wk, Wv, Wv1, Wc1, batch,
                                          xb, WqT, WkT, WvT, Wv1T, Wc1T, smax, seg);
    gemm_kernel<<<1040, 256, 0, stream>>>(xb, smax, Wc1, WqT, WkT, WvT, Wv1T, Wc1T,
                                          bq, bk, bv, bv1, bc1, Wv2, Wc2, batch,
                                          Qb, Kb, Vt, vacc, gcw);
    attn_kernel<<<ATTN_UNITS + 256, 256, 0, stream>>>(xb, Qb, Kb, Vt, seg, Wc1T, bc1,
                                                      gcw, Wc2, batch,
                                                      Opart, Lpart, cacc);
    final_kernel<<<N_NODES, 256, 0, stream>>>(Opart, Lpart, x, vacc, cacc, bv2, bc2,
                                              gamma, beta, batch, seg, out, att);
}